// Round 2
// baseline (468.743 us; speedup 1.0000x reference)
//
#include <hip/hip_runtime.h>
#include <math.h>

#define NN 16384
#define NE 65536
#define HH 128

// ---- constants matching the reference exactly (double, folded to f32) ----
constexpr double D_START = 0.011108996538242306;   // exp(-4.5)
constexpr double D_STEP  = (1.0 - D_START) / 31.0;
constexpr float  F_ALPHA = (float)(5.0/4.5);
constexpr double D_BB    = (2.0/32.0)*(1.0 - D_START);
constexpr float  F_BETA  = (float)(1.0/(D_BB*D_BB));
constexpr float  F_PIC   = (float)(M_PI/4.5);

// fallback scratch pool (used if ws_size too small). ~179 MB needed.
#define POOL_BYTES (192u*1024u*1024u)
__device__ __align__(256) static char g_pool[POOL_BYTES];

__device__ __forceinline__ float wred64(float x){
  #pragma unroll
  for (int o=32;o;o>>=1) x += __shfl_xor(x, o, 64);
  return x;
}
__device__ __forceinline__ float siluf(float x){
  return x * (1.0f/(1.0f + expf(-x)));
}

// ---------------- PZ/QZ precompute: PZ[a][h] = emb_w[a]·emb2_w[h, :128] + b[h]
__global__ __launch_bounds__(128) void k_prez(const float* __restrict__ emb_w,
    const float* __restrict__ emb2_w, const float* __restrict__ emb2_b,
    float* __restrict__ PZ, float* __restrict__ QZ){
  __shared__ float erow[128];
  int a = blockIdx.x, h = threadIdx.x;
  erow[h] = emb_w[a*128 + h];
  __syncthreads();
  float p = 0.f, q = 0.f;
  #pragma unroll 8
  for (int k=0;k<128;++k){
    float e = erow[k];
    p += e * emb2_w[h*256 + k];
    q += e * emb2_w[h*256 + 128 + k];
  }
  PZ[a*128 + h] = p + emb2_b[h];
  QZ[a*128 + h] = q;
}

// ---------------- per-edge: distance, cutoff, RBF, normalized vec; histogram of passing edges
__global__ __launch_bounds__(256) void k_edge(const int* __restrict__ ei,
    const float* __restrict__ pos, const int* __restrict__ z,
    int* __restrict__ counts, int* __restrict__ esrc, int* __restrict__ ezs,
    int* __restrict__ ezd, float* __restrict__ ev, float* __restrict__ eattr){
  int e = blockIdx.x*256 + threadIdx.x;
  if (e >= NE) return;
  int s = ei[e];
  int t = ei[NE + e];
  float dx = pos[3*s+0] - pos[3*t+0];
  float dy = pos[3*s+1] - pos[3*t+1];
  float dz = pos[3*s+2] - pos[3*t+2];
  float d = sqrtf(dx*dx + dy*dy + dz*dz);
  if (d < 4.5f){
    atomicAdd(&counts[s], 1);
    esrc[e] = s;
    ezs[e] = z[s];
    ezd[e] = z[t];
    float denom = (s==t) ? 1.0f : d;
    ev[4*e+0] = dx/denom;
    ev[4*e+1] = dy/denom;
    ev[4*e+2] = dz/denom;
    float cut = 0.5f*(cosf(d*F_PIC) + 1.0f);
    ev[4*e+3] = cut;
    float q = expf(-F_ALPHA*d);
    #pragma unroll
    for (int r=0;r<32;++r){
      float m = (float)(D_START + r*D_STEP);
      float u = q - m;
      eattr[32*e + r] = cut * expf(-F_BETA*u*u);
    }
  } else {
    esrc[e] = -1;
  }
}

// ---------------- exclusive scan of 16384 counts (single block)
__global__ __launch_bounds__(1024) void k_scan(const int* __restrict__ counts,
    int* __restrict__ offsets, int* __restrict__ cursor){
  __shared__ int part[1024];
  int t = threadIdx.x;
  int loc[16];
  int s = 0;
  #pragma unroll
  for (int i=0;i<16;++i){ loc[i] = counts[t*16+i]; s += loc[i]; }
  part[t] = s;
  __syncthreads();
  for (int o=1;o<1024;o<<=1){
    int add = (t>=o) ? part[t-o] : 0;
    __syncthreads();
    part[t] += add;
    __syncthreads();
  }
  int excl = (t==0) ? 0 : part[t-1];
  #pragma unroll
  for (int i=0;i<16;++i){
    offsets[t*16+i] = excl;
    cursor[t*16+i] = excl;
    excl += loc[i];
  }
  if (t==1023) offsets[NN] = excl;
}

// ---------------- scatter passing edges into CSR order
__global__ __launch_bounds__(256) void k_scatter(const int* __restrict__ esrc,
    int* __restrict__ cursor, int* __restrict__ elist){
  int e = blockIdx.x*256 + threadIdx.x;
  if (e >= NE) return;
  int s = esrc[e];
  if (s < 0) return;
  int p = atomicAdd(&cursor[s], 1);
  elist[p] = e;
}

// ---------------- per-node accumulation of I/A/S planes + fused layernorm(tensor_norm)
// block = 128 threads (thread = h), processes 16 nodes
__global__ __launch_bounds__(128) void k_accum(
    const float* __restrict__ dp1, const float* __restrict__ dp2, const float* __restrict__ dp3,
    const float* __restrict__ db1, const float* __restrict__ db2, const float* __restrict__ db3,
    const float* __restrict__ PZ, const float* __restrict__ QZ,
    const int* __restrict__ offsets, const int* __restrict__ elist,
    const int* __restrict__ ezs, const int* __restrict__ ezd,
    const float* __restrict__ ev, const float* __restrict__ eattr,
    const float* __restrict__ gam, const float* __restrict__ bet,
    float* __restrict__ planes, float* __restrict__ tnorm){
  __shared__ float t1[32*130];
  __shared__ float t2[32*130];
  __shared__ float t3[32*130];
  __shared__ float red[4];
  const size_t PL = (size_t)NN*128;
  int h = threadIdx.x;
  for (int i=h; i<4096; i+=128){
    int hh = i>>5, r = i&31;
    t1[r*130+hh] = dp1[i];
    t2[r*130+hh] = dp2[i];
    t3[r*130+hh] = dp3[i];
  }
  __syncthreads();
  float b1 = db1[h], b2 = db2[h], b3 = db3[h];
  float g = gam[h], be = bet[h];
  int wid = h>>6;
  for (int nn=0; nn<16; ++nn){
    int n = blockIdx.x*16 + nn;
    int e0 = offsets[n], e1 = offsets[n+1];
    float w0=0.f, a0=0.f, a1=0.f, a2=0.f;
    float s0=0.f, s1=0.f, s2=0.f, s3=0.f, s4=0.f, s5=0.f;
    for (int j=e0; j<e1; ++j){
      int e = elist[j];
      float att[32];
      #pragma unroll
      for (int r=0;r<32;++r) att[r] = eattr[32*e + r];
      float vx = ev[4*e+0], vy = ev[4*e+1], vz = ev[4*e+2], cut = ev[4*e+3];
      int zs = ezs[e], zd = ezd[e];
      float C = cut * (PZ[zs*128 + h] + QZ[zd*128 + h]);
      float d1 = b1, d2 = b2, d3 = b3;
      #pragma unroll
      for (int r=0;r<32;++r){
        d1 += att[r]*t1[r*130+h];
        d2 += att[r]*t2[r*130+h];
        d3 += att[r]*t3[r*130+h];
      }
      float w = d1*C;  w0 += w;
      float wa = d2*C; a0 += wa*vx; a1 += wa*vy; a2 += wa*vz;
      float ws = d3*C;
      float t3v = (vx*vx + vy*vy + vz*vz)*(1.0f/3.0f);
      s0 += ws*(vx*vx - t3v);
      s1 += ws*(vy*vy - t3v);
      s2 += ws*(vz*vz - t3v);
      s3 += ws*(vx*vy);
      s4 += ws*(vx*vz);
      s5 += ws*(vy*vz);
    }
    size_t idx = (size_t)n*128 + h;
    planes[0*PL+idx]=w0; planes[1*PL+idx]=a0; planes[2*PL+idx]=a1; planes[3*PL+idx]=a2;
    planes[4*PL+idx]=s0; planes[5*PL+idx]=s1; planes[6*PL+idx]=s2;
    planes[7*PL+idx]=s3; planes[8*PL+idx]=s4; planes[9*PL+idx]=s5;
    float tn = 3.f*w0*w0 + 2.f*(a0*a0+a1*a1+a2*a2)
             + (s0*s0+s1*s1+s2*s2) + 2.f*(s3*s3+s4*s4+s5*s5);
    // layernorm over h (2 waves)
    float sm = wred64(tn);
    if ((h&63)==0) red[wid] = sm;
    __syncthreads();
    float mean = (red[0]+red[1])*(1.0f/128.0f);
    float dv = tn - mean;
    float sq = wred64(dv*dv);
    __syncthreads();
    if ((h&63)==0) red[2+wid] = sq;
    __syncthreads();
    float var = (red[2]+red[3])*(1.0f/128.0f);
    tnorm[idx] = dv*(1.0f/sqrtf(var + 1e-5f))*g + be;
  }
}

// ---------------- generic fp32 GEMM: C[M,N] = silu(A[M,K] @ W[N,K]^T + bias)
// block 256, tile 64x64, thread 4x4, K-step 16
__global__ __launch_bounds__(256) void k_gemm(const float* __restrict__ A,
    const float* __restrict__ W, const float* __restrict__ bias,
    float* __restrict__ C, int M, int N, int K){
  __shared__ __align__(16) float As[16*68];
  __shared__ __align__(16) float Ws[16*68];
  int t = threadIdx.x;
  int bm = blockIdx.x*64, bn = blockIdx.y*64;
  int tn = t & 15, tm = t >> 4;
  int lr = t >> 2, lk = (t & 3) << 2;
  float acc[4][4];
  #pragma unroll
  for (int i=0;i<4;++i)
    #pragma unroll
    for (int j=0;j<4;++j) acc[i][j]=0.f;
  for (int kc=0; kc<K; kc+=16){
    float4 av = *(const float4*)&A[(size_t)(bm+lr)*K + kc + lk];
    float4 wv = *(const float4*)&W[(size_t)(bn+lr)*K + kc + lk];
    __syncthreads();
    As[(lk+0)*68+lr]=av.x; As[(lk+1)*68+lr]=av.y; As[(lk+2)*68+lr]=av.z; As[(lk+3)*68+lr]=av.w;
    Ws[(lk+0)*68+lr]=wv.x; Ws[(lk+1)*68+lr]=wv.y; Ws[(lk+2)*68+lr]=wv.z; Ws[(lk+3)*68+lr]=wv.w;
    __syncthreads();
    #pragma unroll
    for (int k=0;k<16;++k){
      float4 a = *(const float4*)&As[k*68 + tm*4];
      float4 w = *(const float4*)&Ws[k*68 + tn*4];
      acc[0][0]+=a.x*w.x; acc[0][1]+=a.x*w.y; acc[0][2]+=a.x*w.z; acc[0][3]+=a.x*w.w;
      acc[1][0]+=a.y*w.x; acc[1][1]+=a.y*w.y; acc[1][2]+=a.y*w.z; acc[1][3]+=a.y*w.w;
      acc[2][0]+=a.z*w.x; acc[2][1]+=a.z*w.y; acc[2][2]+=a.z*w.z; acc[2][3]+=a.z*w.w;
      acc[3][0]+=a.w*w.x; acc[3][1]+=a.w*w.y; acc[3][2]+=a.w*w.z; acc[3][3]+=a.w*w.w;
    }
  }
  float bb[4];
  #pragma unroll
  for (int j=0;j<4;++j) bb[j] = bias[bn + tn*4 + j];
  #pragma unroll
  for (int i=0;i<4;++i){
    int m = bm + tm*4 + i;
    float4 o;
    o.x = siluf(acc[i][0] + bb[0]);
    o.y = siluf(acc[i][1] + bb[1]);
    o.z = siluf(acc[i][2] + bb[2]);
    o.w = siluf(acc[i][3] + bb[3]);
    *(float4*)&C[(size_t)m*N + bn + tn*4] = o;
  }
}

// ---------------- fused mix einsum (10 planes x lt{0,1,2}) + nrm scaling + tensor_norm -> xcat
// block 256: tn = t&15 (node), tkg = t>>4 (8 k's). n-tile 16, full k=128, h staged by 16.
__global__ __launch_bounds__(256) void k_mix(const float* __restrict__ planes,
    const float* __restrict__ lt0, const float* __restrict__ lt1, const float* __restrict__ lt2,
    const float* __restrict__ NRM, float* __restrict__ xcat){
  __shared__ __align__(16) float Pt[10*16*17];
  __shared__ __align__(16) float Wt[3*16*132];
  const size_t PL = (size_t)NN*128;
  int t = threadIdx.x;
  int bn = blockIdx.x*16;
  int tn = t & 15, tkg = t >> 4;
  int k0 = tkg*8;
  float accI[8], accA0[8], accA1[8], accA2[8];
  float accS0[8], accS1[8], accS2[8], accS3[8], accS4[8], accS5[8];
  #pragma unroll
  for (int i=0;i<8;++i){
    accI[i]=0.f; accA0[i]=0.f; accA1[i]=0.f; accA2[i]=0.f;
    accS0[i]=0.f; accS1[i]=0.f; accS2[i]=0.f;
    accS3[i]=0.f; accS4[i]=0.f; accS5[i]=0.f;
  }
  for (int hc=0; hc<128; hc+=16){
    __syncthreads();
    if (t < 64){
      int n0 = t >> 2;
      int h0 = (t & 3) << 2;
      #pragma unroll
      for (int p=0;p<10;++p){
        float4 v = *(const float4*)&planes[p*PL + (size_t)(bn+n0)*128 + hc + h0];
        Pt[p*272 + (h0+0)*17 + n0] = v.x;
        Pt[p*272 + (h0+1)*17 + n0] = v.y;
        Pt[p*272 + (h0+2)*17 + n0] = v.z;
        Pt[p*272 + (h0+3)*17 + n0] = v.w;
      }
    }
    #pragma unroll
    for (int g=0; g<3; ++g){
      const float* lw = (g==0)?lt0:((g==1)?lt1:lt2);
      #pragma unroll
      for (int it=0; it<2; ++it){
        int fi = t + it*256;
        int k = fi >> 2;
        int h0 = (fi & 3) << 2;
        float4 v = *(const float4*)&lw[k*128 + hc + h0];
        Wt[g*2112 + (h0+0)*132 + k] = v.x;
        Wt[g*2112 + (h0+1)*132 + k] = v.y;
        Wt[g*2112 + (h0+2)*132 + k] = v.z;
        Wt[g*2112 + (h0+3)*132 + k] = v.w;
      }
    }
    __syncthreads();
    for (int h=0; h<16; ++h){
      float pv[10];
      #pragma unroll
      for (int p=0;p<10;++p) pv[p] = Pt[p*272 + h*17 + tn];
      float4 x0 = *(const float4*)&Wt[0*2112 + h*132 + k0];
      float4 x1 = *(const float4*)&Wt[0*2112 + h*132 + k0 + 4];
      float4 y0 = *(const float4*)&Wt[1*2112 + h*132 + k0];
      float4 y1 = *(const float4*)&Wt[1*2112 + h*132 + k0 + 4];
      float4 z0 = *(const float4*)&Wt[2*2112 + h*132 + k0];
      float4 z1 = *(const float4*)&Wt[2*2112 + h*132 + k0 + 4];
      float wa[8] = {x0.x,x0.y,x0.z,x0.w,x1.x,x1.y,x1.z,x1.w};
      float wb[8] = {y0.x,y0.y,y0.z,y0.w,y1.x,y1.y,y1.z,y1.w};
      float wc[8] = {z0.x,z0.y,z0.z,z0.w,z1.x,z1.y,z1.z,z1.w};
      #pragma unroll
      for (int i=0;i<8;++i){
        accI[i]  += pv[0]*wa[i];
        accA0[i] += pv[1]*wb[i];
        accA1[i] += pv[2]*wb[i];
        accA2[i] += pv[3]*wb[i];
        accS0[i] += pv[4]*wc[i];
        accS1[i] += pv[5]*wc[i];
        accS2[i] += pv[6]*wc[i];
        accS3[i] += pv[7]*wc[i];
        accS4[i] += pv[8]*wc[i];
        accS5[i] += pv[9]*wc[i];
      }
    }
  }
  int n = bn + tn;
  #pragma unroll
  for (int i=0;i<8;++i){
    int k = k0 + i;
    float n0 = NRM[(size_t)n*384 + k*3 + 0];
    float n1 = NRM[(size_t)n*384 + k*3 + 1];
    float n2 = NRM[(size_t)n*384 + k*3 + 2];
    float tI = accI[i]*n0;
    float xI = 3.f*tI*tI;
    float ta0 = accA0[i]*n1, ta1 = accA1[i]*n1, ta2 = accA2[i]*n1;
    float xA = 2.f*(ta0*ta0 + ta1*ta1 + ta2*ta2);
    float td0 = accS0[i]*n2, td1 = accS1[i]*n2, td2 = accS2[i]*n2;
    float to0 = accS3[i]*n2, to1 = accS4[i]*n2, to2 = accS5[i]*n2;
    float xS = td0*td0 + td1*td1 + td2*td2 + 2.f*(to0*to0 + to1*to1 + to2*to2);
    xcat[(size_t)n*384 + k]       = xI;
    xcat[(size_t)n*384 + 128 + k] = xA;
    xcat[(size_t)n*384 + 256 + k] = xS;
  }
}

// ---------------- layernorm over 384, in place (wave per node)
__global__ __launch_bounds__(256) void k_ln2(float* __restrict__ xcat,
    const float* __restrict__ gam, const float* __restrict__ bet){
  int wid = threadIdx.x >> 6, l = threadIdx.x & 63;
  int n = blockIdx.x*4 + wid;
  float v[6];
  float s = 0.f;
  #pragma unroll
  for (int i=0;i<6;++i){ v[i] = xcat[(size_t)n*384 + i*64 + l]; s += v[i]; }
  s = wred64(s);
  float mean = s*(1.0f/384.0f);
  float q = 0.f;
  #pragma unroll
  for (int i=0;i<6;++i){ float d = v[i]-mean; q += d*d; }
  q = wred64(q);
  float rstd = 1.0f/sqrtf(q*(1.0f/384.0f) + 1e-5f);
  #pragma unroll
  for (int i=0;i<6;++i){
    int c = i*64 + l;
    xcat[(size_t)n*384 + c] = (v[i]-mean)*rstd*gam[c] + bet[c];
  }
}

// ---------------- head: silu(X3 @ ol1^T + b1) @ ol2^T + b2 -> y   (wave per node)
__global__ __launch_bounds__(256) void k_head(const float* __restrict__ X3,
    const float* __restrict__ ol1w, const float* __restrict__ ol1b,
    const float* __restrict__ ol2w, const float* __restrict__ ol2b,
    float* __restrict__ y){
  __shared__ float olT[128*64];
  __shared__ float o2[64];
  __shared__ float o1b[64];
  int t = threadIdx.x;
  for (int i=t; i<8192; i+=256){
    int j = i >> 7, ii = i & 127;
    olT[ii*64 + j] = ol1w[i];
  }
  if (t < 64){ o2[t] = ol2w[t]; o1b[t] = ol1b[t]; }
  __syncthreads();
  int wid = t >> 6, l = t & 63;
  float b2 = ol2b[0];
  for (int c=0; c<16; ++c){
    int n = blockIdx.x*64 + c*4 + wid;
    float acc = o1b[l];
    #pragma unroll 8
    for (int i=0;i<128;++i) acc += X3[(size_t)n*128 + i] * olT[i*64 + l];
    float sv = siluf(acc) * o2[l];
    sv = wred64(sv);
    if (l==0) y[n] = sv + b2;
  }
}

extern "C" void kernel_launch(void* const* d_in, const int* in_sizes, int n_in,
                              void* d_out, int out_size, void* d_ws, size_t ws_size,
                              hipStream_t stream) {
  const int*   z      = (const int*)d_in[0];
  const float* pos    = (const float*)d_in[1];
  const int*   ei     = (const int*)d_in[3];   // int64 in reference -> int32 from harness
  const float* emb_w  = (const float*)d_in[4];
  const float* emb2_w = (const float*)d_in[5];
  const float* emb2_b = (const float*)d_in[6];
  const float* dp1_w  = (const float*)d_in[7];
  const float* dp1_b  = (const float*)d_in[8];
  const float* dp2_w  = (const float*)d_in[9];
  const float* dp2_b  = (const float*)d_in[10];
  const float* dp3_w  = (const float*)d_in[11];
  const float* dp3_b  = (const float*)d_in[12];
  const float* lt0_w  = (const float*)d_in[13];
  const float* lt1_w  = (const float*)d_in[14];
  const float* lt2_w  = (const float*)d_in[15];
  const float* ls0_w  = (const float*)d_in[16];
  const float* ls0_b  = (const float*)d_in[17];
  const float* ls1_w  = (const float*)d_in[18];
  const float* ls1_b  = (const float*)d_in[19];
  const float* in_g   = (const float*)d_in[20];
  const float* in_b   = (const float*)d_in[21];
  const float* lin_w  = (const float*)d_in[22];
  const float* lin_b  = (const float*)d_in[23];
  const float* on_g   = (const float*)d_in[24];
  const float* on_b   = (const float*)d_in[25];
  const float* ol1_w  = (const float*)d_in[26];
  const float* ol1_b  = (const float*)d_in[27];
  const float* ol2_w  = (const float*)d_in[28];
  const float* ol2_b  = (const float*)d_in[29];
  float* out = (float*)d_out;

  // scratch: prefer d_ws, fall back to static device pool if too small (~179 MB needed)
  const size_t NEED = 180u*1024u*1024u;
  char* wsb = (char*)d_ws;
  if (ws_size < NEED){
    void* p = nullptr;
    hipGetSymbolAddress(&p, HIP_SYMBOL(g_pool));
    wsb = (char*)p;
  }
  size_t off = 0;
  auto alloc = [&](size_t bytes)->void*{
    void* p = wsb + off;
    off = (off + bytes + 255) & ~(size_t)255;
    return p;
  };
  float* PZ      = (float*)alloc(128*128*4);
  float* QZ      = (float*)alloc(128*128*4);
  int*   counts  = (int*)  alloc(NN*4);
  int*   offsets = (int*)  alloc((NN+1)*4);
  int*   cursor  = (int*)  alloc(NN*4);
  int*   esrc    = (int*)  alloc(NE*4);
  int*   ezs     = (int*)  alloc(NE*4);
  int*   ezd     = (int*)  alloc(NE*4);
  int*   elist   = (int*)  alloc(NE*4);
  float* ev      = (float*)alloc((size_t)NE*4*4);
  float* eattr   = (float*)alloc((size_t)NE*32*4);
  float* planes  = (float*)alloc((size_t)10*NN*128*4);
  float* tnorm   = (float*)alloc((size_t)NN*128*4);
  float* T1      = (float*)alloc((size_t)NN*256*4);
  float* NRM     = (float*)alloc((size_t)NN*384*4);
  float* xcat    = (float*)alloc((size_t)NN*384*4);
  float* X3      = (float*)alloc((size_t)NN*128*4);

  hipMemsetAsync(counts, 0, NN*4, stream);

  k_prez<<<128, 128, 0, stream>>>(emb_w, emb2_w, emb2_b, PZ, QZ);
  k_edge<<<NE/256, 256, 0, stream>>>(ei, pos, z, counts, esrc, ezs, ezd, ev, eattr);
  k_scan<<<1, 1024, 0, stream>>>(counts, offsets, cursor);
  k_scatter<<<NE/256, 256, 0, stream>>>(esrc, cursor, elist);
  k_accum<<<NN/16, 128, 0, stream>>>(dp1_w, dp2_w, dp3_w, dp1_b, dp2_b, dp3_b,
                                     PZ, QZ, offsets, elist, ezs, ezd, ev, eattr,
                                     in_g, in_b, planes, tnorm);
  // nrm = silu(silu(tnorm @ ls0^T + b) @ ls1^T + b)
  {
    dim3 g1(NN/64, 256/64);
    k_gemm<<<g1, 256, 0, stream>>>(tnorm, ls0_w, ls0_b, T1, NN, 256, 128);
    dim3 g2(NN/64, 384/64);
    k_gemm<<<g2, 256, 0, stream>>>(T1, ls1_w, ls1_b, NRM, NN, 384, 256);
  }
  k_mix<<<NN/16, 256, 0, stream>>>(planes, lt0_w, lt1_w, lt2_w, NRM, xcat);
  k_ln2<<<NN/4, 256, 0, stream>>>(xcat, on_g, on_b);
  {
    dim3 g3(NN/64, 128/64);
    k_gemm<<<g3, 256, 0, stream>>>(xcat, lin_w, lin_b, X3, NN, 128, 384);
  }
  k_head<<<NN/64, 256, 0, stream>>>(X3, ol1_w, ol1_b, ol2_w, ol2_b, out);
}